// Round 5
// baseline (339.668 us; speedup 1.0000x reference)
//
#include <hip/hip_runtime.h>
#include <cstddef>

#define D   64
#define L   128
#define NT  64             // ONE wave per block
#define ROWS 16            // one M=16 MFMA tile per block (one stream)
#define XSS 132            // padded floats (mult of 4 keeps float4 alignment)
#define HBS 72             // shorts
#define NBLK 512           // 8192 / 16
#define LOG2E 1.4426950408889634f

typedef __attribute__((ext_vector_type(8))) short short8;
typedef __attribute__((ext_vector_type(4))) float floatx4;
typedef __attribute__((ext_vector_type(2))) float f2;

__device__ __forceinline__ float fast_rcp(float x) {
#if defined(__has_builtin)
#if __has_builtin(__builtin_amdgcn_rcpf)
  return __builtin_amdgcn_rcpf(x);
#else
  return 1.0f / x;
#endif
#else
  return 1.0f / x;
#endif
}
__device__ __forceinline__ float ex2(float x) {
#if defined(__has_builtin)
#if __has_builtin(__builtin_amdgcn_exp2f)
  return __builtin_amdgcn_exp2f(x);
#else
  return __builtin_exp2f(x);
#endif
#else
  return __builtin_exp2f(x);
#endif
}
__device__ __forceinline__ f2 ex2_2(f2 v) { return (f2){ex2(v.x), ex2(v.y)}; }
__device__ __forceinline__ f2 rcp_2(f2 v) { return (f2){fast_rcp(v.x), fast_rcp(v.y)}; }
__device__ __forceinline__ float sig_plain(float x) {
  return fast_rcp(1.0f + ex2(-LOG2E * x));
}
__device__ __forceinline__ float tanh2(float G) {   // tanh(x), G = -2log2e*x
  return fmaf(2.0f, fast_rcp(1.0f + ex2(G)), -1.0f);
}
__device__ __forceinline__ unsigned short f2bf_rtne(float f) {
  unsigned int u = __float_as_uint(f);
  u += 0x7fffu + ((u >> 16) & 1u);
  return (unsigned short)(u >> 16);
}

// R16: barrier-free single-wave streams.
// R14/R15 post-mortem: scheduler-TLP (R11), in-wave sequential streams
// (R14) and SLP-forced interleave (R15) all land at ~1100-1200 cyc per
// 16-row step with VALUBusy pinned at 42-45% -- the exposed stall is the
// barrier-synced cross-wave h-exchange itself (write h -> waitcnt drain
// -> s_barrier -> ds_read -> dependent MFMA), unhideable by instruction
// rearrangement. Fix: ONE wave owns the whole recurrence for its 16
// rows: all 4 gates x all 64 cols = 16 MFMA tiles (cols interleaved
// 4*c16+dt so each lane's 4 cell-cols are contiguous -> h write is one
// b64 per row). h stays wave-private: LDS transpose buffer, same-wave
// in-order DS => NO __syncthreads in the recurrence at all. Grid:
// 512 blocks x 64 thr = 2 single-wave blocks/CU. Same MFMA order, same
// ew op order per cell, same RTNE pack, tail reproduces R11's exact
// fmaf chains + quad shuffle tree -> bit-identical (absmax 8.0).
// VGPR deliberately high (Bf 128 + acc 64); launch_bounds(64,1) allows
// up to 512 per wave at 1 wave/SIMD. Spill tripwire: WRITE_SIZE.
__global__ __launch_bounds__(NT, 1)
void lstm_main(const float* __restrict__ x,
               const float* __restrict__ W_num,
               const float* __restrict__ b_num,
               const float* __restrict__ W_ih,
               const float* __restrict__ W_hh,
               const float* __restrict__ b_ih,
               const float* __restrict__ b_hh,
               const float* __restrict__ W_aout,
               const float* __restrict__ b_aout,
               const float* __restrict__ W_fh,
               const float* __restrict__ b_fh,
               const float* __restrict__ W_iouh,
               const float* __restrict__ b_iouh,
               const float* __restrict__ W_oout,
               const float* __restrict__ b_oout,
               float* __restrict__ acc_out,   // [0..63]=fc, [64..127]=hs, [128]=ticket
               float* __restrict__ out)
{
  __shared__ __align__(16) float xs[ROWS * XSS];   // 8.25 KB (x; later h/h_hat)
  __shared__ __align__(16) short hb[ROWS * HBS];   // 2.25 KB bf16 h (single buffer)
  __shared__ float sacc[2 * D];
  __shared__ float hobj[D];
  __shared__ int   is_last;

  const int tid  = threadIdx.x;     // 0..63 == lane
  const int quad = tid >> 4;
  const int c16  = tid & 15;
  const int k0   = blockIdx.x * ROWS;
  const int col0 = 4 * c16;         // this lane's 4 cell-cols: col0..col0+3

  // ---- stage x tile (16 rows x 128), coalesced, 64 threads ----
  for (int i = tid; i < ROWS * (L / 4); i += NT) {
    int r = i >> 5, c4 = i & 31;
    float4 v = ((const float4*)(x + (size_t)(k0 + r) * L))[c4];
    float* dst = &xs[r * XSS + c4 * 4];
    dst[0] = v.x; dst[1] = v.y; dst[2] = v.z; dst[3] = v.w;
  }
  for (int i = tid; i < ROWS * HBS; i += NT) hb[i] = 0;

  // per-gate exp2 prescale (g-gate feeds tanh -> -2log2e)
  const float gscale[4] = {-LOG2E, -LOG2E, -2.0f * LOG2E, -LOG2E};

  // ---- preload W_num/b_num once (reused by all 16 tiles) ----
  float4 wn[16], bn[16];
#pragma unroll
  for (int e4 = 0; e4 < 16; ++e4) {
    wn[e4] = ((const float4*)W_num)[e4];
    bn[e4] = ((const float4*)b_num)[e4];
  }

  // ---- rank-1 x-projection constants (prescaled): 16 tiles ----
  // tile t: gate g = t>>2, col-subtile dt = t&3, gate-col j = g*64+col0+dt
  float An[16], Bc[16];
#pragma unroll
  for (int t = 0; t < 16; ++t) {
    int j = (t >> 2) * 64 + col0 + (t & 3);
    const float4* wr = (const float4*)(W_ih + (size_t)j * (2 * D));
    float a = 0.0f, b = b_ih[j] + b_hh[j];
#pragma unroll
    for (int e4 = 0; e4 < 16; ++e4) {
      float4 wv = wr[e4];
      a = fmaf(wn[e4].x, wv.x, a); a = fmaf(wn[e4].y, wv.y, a);
      a = fmaf(wn[e4].z, wv.z, a); a = fmaf(wn[e4].w, wv.w, a);
      b = fmaf(bn[e4].x, wv.x, b); b = fmaf(bn[e4].y, wv.y, b);
      b = fmaf(bn[e4].z, wv.z, b); b = fmaf(bn[e4].w, wv.w, b);
    }
    An[t] = a * gscale[t >> 2]; Bc[t] = b * gscale[t >> 2];
  }

  // ---- W_hh B-fragments for all 16 tiles (prescaled RTNE bf16) ----
  short8 Bf[16][2];
#pragma unroll
  for (int t = 0; t < 16; ++t) {
#pragma unroll
    for (int kk = 0; kk < 2; ++kk) {
      const float4* wp = (const float4*)(W_hh
          + (size_t)((t >> 2) * 64 + col0 + (t & 3)) * D + kk * 32 + quad * 8);
      float wv[8];
      float4 w0 = wp[0], w1 = wp[1];
      wv[0]=w0.x; wv[1]=w0.y; wv[2]=w0.z; wv[3]=w0.w;
      wv[4]=w1.x; wv[5]=w1.y; wv[6]=w1.z; wv[7]=w1.w;
      short8 hi8;
#pragma unroll
      for (int j = 0; j < 8; ++j)
        hi8[j] = (short)f2bf_rtne(wv[j] * gscale[t >> 2]);
      Bf[t][kk] = hi8;
    }
  }

  const f2 one2 = {1.0f, 1.0f};
  const f2 m2l2 = {-2.0f * LOG2E, -2.0f * LOG2E};
  // creg2[dt][h] = cells (rows 2h,2h+1 of this quad's 4 rows) at col col0+dt
  f2 creg2[4][2] = {{{0.f,0.f},{0.f,0.f}}, {{0.f,0.f},{0.f,0.f}},
                    {{0.f,0.f},{0.f,0.f}}, {{0.f,0.f},{0.f,0.f}}};
  f2 hreg2[4][2] = {{{0.f,0.f},{0.f,0.f}}, {{0.f,0.f},{0.f,0.f}},
                    {{0.f,0.f},{0.f,0.f}}, {{0.f,0.f},{0.f,0.f}}};
  __syncthreads();   // single wave: near-free; orders staging vs loop

  for (int t4 = 0; t4 < L; t4 += 4) {
    // 4 steps' worth of x per row in one b128 each
    float4 xq[4];
#pragma unroll
    for (int r = 0; r < 4; ++r)
      xq[r] = *(const float4*)&xs[(quad * 4 + r) * XSS + t4];
#pragma unroll
    for (int u = 0; u < 4; ++u) {
      // A-fragment of h(t-1): m=c16, k=kk*32+quad*8+j. Same-wave DS is
      // in-order: these reads see last step's writes, no barrier needed.
      short8 ahi[2];
#pragma unroll
      for (int kk = 0; kk < 2; ++kk)
        ahi[kk] = *(const short8*)&hb[c16 * HBS + kk * 32 + quad * 8];
      f2 xv01 = {xq[0][u], xq[1][u]};
      f2 xv23 = {xq[2][u], xq[3][u]};
      floatx4 acc[16];
#pragma unroll
      for (int t = 0; t < 16; ++t) {
        f2 A2 = {An[t], An[t]}, B2 = {Bc[t], Bc[t]};
        f2 i01 = A2 * xv01 + B2;        // v_pk_fma_f32
        f2 i23 = A2 * xv23 + B2;
        acc[t] = (floatx4){i01.x, i01.y, i23.x, i23.y};
      }
#pragma unroll
      for (int kk = 0; kk < 2; ++kk) {
#pragma unroll
        for (int t = 0; t < 16; ++t)
          acc[t] = __builtin_amdgcn_mfma_f32_16x16x32_bf16(ahi[kk], Bf[t][kk], acc[t], 0, 0, 0);
      }
      // merged elementwise on cell PAIRS (rows 2h,2h+1 at col col0+dt):
      // identical op order per cell as R11 -> bit-identical
#pragma unroll
      for (int dt = 0; dt < 4; ++dt) {
#pragma unroll
        for (int h = 0; h < 2; ++h) {
          f2 Gi = {acc[dt][2*h],      acc[dt][2*h+1]};
          f2 Gf = {acc[4 + dt][2*h],  acc[4 + dt][2*h+1]};
          f2 Gg = {acc[8 + dt][2*h],  acc[8 + dt][2*h+1]};
          f2 Go = {acc[12 + dt][2*h], acc[12 + dt][2*h+1]};
          f2 Ei = ex2_2(Gi), Ef = ex2_2(Gf), Eg = ex2_2(Gg), Eo = ex2_2(Go);
          f2 pf = Ef + one2, pi = Ei + one2, pg = Eg + one2, mg = one2 - Eg;
          f2 pig = pi * pg;
          f2 num = creg2[dt][h] * pig + mg * pf;
          f2 c2  = num * rcp_2(pf * pig);
          creg2[dt][h] = c2;
          f2 Ec = ex2_2(c2 * m2l2);
          f2 po = Eo + one2, pc = Ec + one2, mc = one2 - Ec;
          f2 h2 = mc * rcp_2(po * pc);
          hreg2[dt][h] = h2;
        }
      }
      // write h(t): per row one b64 (4 contiguous bf16 cols col0..col0+3)
#pragma unroll
      for (int r = 0; r < 4; ++r) {
        float h0 = (r & 1) ? hreg2[0][r >> 1].y : hreg2[0][r >> 1].x;
        float h1 = (r & 1) ? hreg2[1][r >> 1].y : hreg2[1][r >> 1].x;
        float h2v = (r & 1) ? hreg2[2][r >> 1].y : hreg2[2][r >> 1].x;
        float h3 = (r & 1) ? hreg2[3][r >> 1].y : hreg2[3][r >> 1].x;
        unsigned int b0 = (unsigned int)f2bf_rtne(h0) | ((unsigned int)f2bf_rtne(h1) << 16);
        unsigned int b1 = (unsigned int)f2bf_rtne(h2v) | ((unsigned int)f2bf_rtne(h3) << 16);
        unsigned long long wv = (unsigned long long)b0 | ((unsigned long long)b1 << 32);
        *(unsigned long long*)(&hb[(quad * 4 + r) * HBS + col0]) = wv;
      }
      // NO barrier: next step's reads are same-wave, in-order after these writes
    }
  }

  // ---- tail: h_hat = h@W_aout.T+b ; f = h_hat@W_fh.T+b ; partial sums ----
  // x tile dead: xs[row][0..63] = h fp32, xs[row][64..127] = h_hat
#pragma unroll
  for (int r = 0; r < 4; ++r) {
    float4 hv;
    hv.x = (r & 1) ? hreg2[0][r >> 1].y : hreg2[0][r >> 1].x;
    hv.y = (r & 1) ? hreg2[1][r >> 1].y : hreg2[1][r >> 1].x;
    hv.z = (r & 1) ? hreg2[2][r >> 1].y : hreg2[2][r >> 1].x;
    hv.w = (r & 1) ? hreg2[3][r >> 1].y : hreg2[3][r >> 1].x;
    *(float4*)&xs[(quad * 4 + r) * XSS + col0] = hv;
  }
  __syncthreads();

  // h_hat[r][dt] for rows quad*4+r, cols col0+dt — same fmaf chain as R11
  float hhat[4][4];
#pragma unroll
  for (int dt = 0; dt < 4; ++dt) {
    const int col = col0 + dt;
    const float4* wa = (const float4*)(W_aout + (size_t)col * D);
#pragma unroll
    for (int r = 0; r < 4; ++r) {
      float a = b_aout[col];
      const float* hp = &xs[(quad * 4 + r) * XSS];
#pragma unroll
      for (int e4 = 0; e4 < 16; ++e4) {
        float4 wv = wa[e4];
        a = fmaf(wv.x, hp[e4*4+0], a); a = fmaf(wv.y, hp[e4*4+1], a);
        a = fmaf(wv.z, hp[e4*4+2], a); a = fmaf(wv.w, hp[e4*4+3], a);
      }
      hhat[r][dt] = a;
    }
  }
  __syncthreads();
#pragma unroll
  for (int r = 0; r < 4; ++r) {
    float4 hv = {hhat[r][0], hhat[r][1], hhat[r][2], hhat[r][3]};
    *(float4*)&xs[(quad * 4 + r) * XSS + 64 + col0] = hv;
  }
  __syncthreads();

  float pfc[4] = {0.f, 0.f, 0.f, 0.f}, phs[4] = {0.f, 0.f, 0.f, 0.f};
#pragma unroll
  for (int dt = 0; dt < 4; ++dt) {
    const int col = col0 + dt;
    const float4* wf = (const float4*)(W_fh + (size_t)col * D);
#pragma unroll
    for (int r = 0; r < 4; ++r) {
      float f = b_fh[col];
      const float* hp = &xs[(quad * 4 + r) * XSS + 64];
#pragma unroll
      for (int e4 = 0; e4 < 16; ++e4) {
        float4 wv = wf[e4];
        f = fmaf(wv.x, hp[e4*4+0], f); f = fmaf(wv.y, hp[e4*4+1], f);
        f = fmaf(wv.z, hp[e4*4+2], f); f = fmaf(wv.w, hp[e4*4+3], f);
      }
      float cv = (r & 1) ? creg2[dt][r >> 1].y : creg2[dt][r >> 1].x;
      pfc[dt] = fmaf(sig_plain(f), cv, pfc[dt]);
      phs[dt] += hhat[r][dt];
    }
  }
  // same quad-combining tree as R11: ((q0+q1)+(q2+q3)) via xor 16, 32
#pragma unroll
  for (int dt = 0; dt < 4; ++dt) {
    pfc[dt] += __shfl_xor(pfc[dt], 16); pfc[dt] += __shfl_xor(pfc[dt], 32);
    phs[dt] += __shfl_xor(phs[dt], 16); phs[dt] += __shfl_xor(phs[dt], 32);
  }
  if (quad == 0) {
#pragma unroll
    for (int dt = 0; dt < 4; ++dt) {
      atomicAdd(acc_out + col0 + dt, pfc[dt]);
      atomicAdd(acc_out + D + col0 + dt, phs[dt]);
    }
  }

  // ---- last-block finish ----
  __threadfence();
  if (tid == 0) {
    unsigned int prev = __hip_atomic_fetch_add((unsigned int*)(acc_out + 2 * D), 1u,
                                               __ATOMIC_ACQ_REL, __HIP_MEMORY_SCOPE_AGENT);
    is_last = (prev == NBLK - 1) ? 1 : 0;
  }
  __syncthreads();
  if (!is_last) return;
  __threadfence();
  for (int i = tid; i < 2 * D; i += NT)
    sacc[i] = __hip_atomic_load(acc_out + i, __ATOMIC_RELAXED, __HIP_MEMORY_SCOPE_AGENT);
  __syncthreads();
  {
    const int d = tid;          // NT == D == 64
    float vi = b_iouh[d], vo = b_iouh[D + d], vu = b_iouh[2 * D + d];
    for (int e = 0; e < D; ++e) {
      float hs = sacc[D + e];
      vi = fmaf(W_iouh[(size_t)d * D + e],           hs, vi);
      vo = fmaf(W_iouh[(size_t)(D + d) * D + e],     hs, vo);
      vu = fmaf(W_iouh[(size_t)(2 * D + d) * D + e], hs, vu);
    }
    float c_obj = sig_plain(vi) * tanh2(-2.0f * LOG2E * vu) + sacc[d];
    float h_obj = sig_plain(vo) * tanh2(-2.0f * LOG2E * c_obj);
    hobj[d] = h_obj;
    out[D + d] = c_obj;
  }
  __syncthreads();
  {
    const int d = tid;
    float hh = b_oout[d];
    for (int e = 0; e < D; ++e) hh = fmaf(W_oout[(size_t)d * D + e], hobj[e], hh);
    out[d] = hh;
  }
}

extern "C" void kernel_launch(void* const* d_in, const int* in_sizes, int n_in,
                              void* d_out, int out_size, void* d_ws, size_t ws_size,
                              hipStream_t stream) {
  const float* x      = (const float*)d_in[0];
  const float* W_num  = (const float*)d_in[1];
  const float* b_num  = (const float*)d_in[2];
  const float* W_ih   = (const float*)d_in[3];
  const float* W_hh   = (const float*)d_in[4];
  const float* b_ih   = (const float*)d_in[5];
  const float* b_hh   = (const float*)d_in[6];
  const float* W_aout = (const float*)d_in[7];
  const float* b_aout = (const float*)d_in[8];
  const float* W_fh   = (const float*)d_in[9];
  const float* b_fh   = (const float*)d_in[10];
  const float* W_iouh = (const float*)d_in[11];
  const float* b_iouh = (const float*)d_in[12];
  const float* W_oout = (const float*)d_in[13];
  const float* b_oout = (const float*)d_in[14];
  float* acc = (float*)d_ws;
  float* out = (float*)d_out;

  hipMemsetAsync(d_ws, 0, (2 * D + 1) * sizeof(float), stream);
  lstm_main<<<NBLK, NT, 0, stream>>>(x, W_num, b_num, W_ih, W_hh, b_ih, b_hh,
                                     W_aout, b_aout, W_fh, b_fh,
                                     W_iouh, b_iouh, W_oout, b_oout, acc, out);
}

// Round 6
// 201.613 us; speedup vs baseline: 1.6848x; 1.6848x over previous
//
#include <hip/hip_runtime.h>
#include <cstddef>

#define D   64
#define L   128
#define NT  256            // 4 waves per block (R11 winner config)
#define ROWS 16            // one M=16 MFMA tile per block
#define XSS 132            // padded floats (mult of 4 keeps float4 alignment)
#define HBS 72             // shorts
#define NBLK 512           // 8192 / 16
#define LOG2E 1.4426950408889634f

typedef __attribute__((ext_vector_type(8))) short short8;
typedef __attribute__((ext_vector_type(4))) float floatx4;
typedef __attribute__((ext_vector_type(2))) float f2;

__device__ __forceinline__ float fast_rcp(float x) {
#if defined(__has_builtin)
#if __has_builtin(__builtin_amdgcn_rcpf)
  return __builtin_amdgcn_rcpf(x);
#else
  return 1.0f / x;
#endif
#else
  return 1.0f / x;
#endif
}
__device__ __forceinline__ float ex2(float x) {
#if defined(__has_builtin)
#if __has_builtin(__builtin_amdgcn_exp2f)
  return __builtin_amdgcn_exp2f(x);
#else
  return __builtin_exp2f(x);
#endif
#else
  return __builtin_exp2f(x);
#endif
}
__device__ __forceinline__ f2 ex2_2(f2 v) { return (f2){ex2(v.x), ex2(v.y)}; }
__device__ __forceinline__ f2 rcp_2(f2 v) { return (f2){fast_rcp(v.x), fast_rcp(v.y)}; }
__device__ __forceinline__ float sig_plain(float x) {
  return fast_rcp(1.0f + ex2(-LOG2E * x));
}
__device__ __forceinline__ float tanh2(float G) {   // tanh(x), G = -2log2e*x
  return fmaf(2.0f, fast_rcp(1.0f + ex2(G)), -1.0f);
}
__device__ __forceinline__ unsigned short f2bf_rtne(float f) {
  unsigned int u = __float_as_uint(f);
  u += 0x7fffu + ((u >> 16) & 1u);
  return (unsigned short)(u >> 16);
}
__device__ __forceinline__ float bf2f(unsigned short s) {
  return __uint_as_float(((unsigned int)s) << 16);
}

// R17 = byte-identical R11 main body (the 132us winner: 512 blk x 4
// waves = 2 blocks/CU, 2 waves/SIMD, gates register-resident, ONE
// barrier/step) + anti-phase stagger AT KERNEL TOP.
//
// R13's stagger was confounded: placed after weight preload, the branch
// split An/Bc/Bf live ranges -> VGPR 64->128 + 41MB scratch. Here the
// stagger runs before ANY staging/preload (only blockIdx live), as a
// SALU-only s_sleep loop -> zero register-allocation impact. Parity
// XOR-folds blockIdx bits 0/3/8 so linear, CU-modulo, and XCD-modulo
// co-residency pairings all land anti-phased (~1024 clk =~ half a step).
// Discriminates phase-lock model (predict 100-115us) vs issue/chain
// model (predict 132us flat). Pure delay -> numerics identical,
// absmax must stay 8.0. Tripwires: VGPR=64, FETCH~2850KB, WRITE~272KB.
__global__ __launch_bounds__(NT, 2)
void lstm_main(const float* __restrict__ x,
               const float* __restrict__ W_num,
               const float* __restrict__ b_num,
               const float* __restrict__ W_ih,
               const float* __restrict__ W_hh,
               const float* __restrict__ b_ih,
               const float* __restrict__ b_hh,
               const float* __restrict__ W_aout,
               const float* __restrict__ b_aout,
               const float* __restrict__ W_fh,
               const float* __restrict__ b_fh,
               const float* __restrict__ W_iouh,
               const float* __restrict__ b_iouh,
               const float* __restrict__ W_oout,
               const float* __restrict__ b_oout,
               float* __restrict__ acc_out,   // [0..63]=fc, [64..127]=hs, [128]=ticket
               float* __restrict__ out)
{
  __shared__ __align__(16) float xs[ROWS * XSS];       // 8.25 KB (x; later h/h_hat)
  __shared__ __align__(16) short hb[2][ROWS * HBS];    // 4.5 KB double-buffered bf16 h
  __shared__ float sacc[2 * D];
  __shared__ float hobj[D];
  __shared__ int   is_last;

  // ---- R17 stagger: FIRST thing in the kernel, SALU-only ----
  {
    const unsigned int b = blockIdx.x;
    int stg = (int)((b ^ (b >> 3) ^ (b >> 8)) & 1u) << 3;   // 0 or 8 iters
    for (int i = 0; i < stg; ++i) __builtin_amdgcn_s_sleep(2);  // ~8*128 clk
  }

  const int tid  = threadIdx.x;
  const int w    = tid >> 6;
  const int lane = tid & 63;
  const int quad = lane >> 4;
  const int c16  = lane & 15;
  const int k0   = blockIdx.x * ROWS;
  const int dcol = w * 16 + c16;

  // ---- stage x tile (16 rows x 128), coalesced ----
  for (int i = tid; i < ROWS * (L / 4); i += NT) {
    int r = i >> 5, c4 = i & 31;
    float4 v = ((const float4*)(x + (size_t)(k0 + r) * L))[c4];
    float* dst = &xs[r * XSS + c4 * 4];
    dst[0] = v.x; dst[1] = v.y; dst[2] = v.z; dst[3] = v.w;
  }
  for (int i = tid; i < ROWS * HBS; i += NT) hb[0][i] = 0;

  // per-gate exp2 prescale (g-gate feeds tanh -> -2log2e)
  const float gscale[4] = {-LOG2E, -LOG2E, -2.0f * LOG2E, -LOG2E};

  // ---- rank-1 x-projection constants (prescaled), float4 loads ----
  float An[4], Bc[4];
#pragma unroll
  for (int g = 0; g < 4; ++g) {
    int j = g * 64 + dcol;
    const float4* wr = (const float4*)(W_ih + (size_t)j * (2 * D));
    float a = 0.0f, b = b_ih[j] + b_hh[j];
#pragma unroll
    for (int e4 = 0; e4 < 16; ++e4) {
      float4 wv = wr[e4];
      float4 wn = ((const float4*)W_num)[e4];
      float4 bn = ((const float4*)b_num)[e4];
      a = fmaf(wn.x, wv.x, a); a = fmaf(wn.y, wv.y, a);
      a = fmaf(wn.z, wv.z, a); a = fmaf(wn.w, wv.w, a);
      b = fmaf(bn.x, wv.x, b); b = fmaf(bn.y, wv.y, b);
      b = fmaf(bn.z, wv.z, b); b = fmaf(bn.w, wv.w, b);
    }
    An[g] = a * gscale[g]; Bc[g] = b * gscale[g];
  }

  // ---- W_hh B-fragments (prescaled, single RTNE bf16, constant) ----
  short8 Bf[4][2];
#pragma unroll
  for (int g = 0; g < 4; ++g) {
#pragma unroll
    for (int kk = 0; kk < 2; ++kk) {
      const float4* wp = (const float4*)(W_hh + (size_t)(g * 64 + dcol) * D
                                         + kk * 32 + quad * 8);
      float wv[8];
      float4 w0 = wp[0], w1 = wp[1];
      wv[0]=w0.x; wv[1]=w0.y; wv[2]=w0.z; wv[3]=w0.w;
      wv[4]=w1.x; wv[5]=w1.y; wv[6]=w1.z; wv[7]=w1.w;
      short8 hi8;
#pragma unroll
      for (int j = 0; j < 8; ++j)
        hi8[j] = (short)f2bf_rtne(wv[j] * gscale[g]);
      Bf[g][kk] = hi8;
    }
  }

  const f2 one2  = {1.0f, 1.0f};
  const f2 m2l2  = {-2.0f * LOG2E, -2.0f * LOG2E};
  f2 creg2[2] = {{0.f, 0.f}, {0.f, 0.f}};   // cell pairs (r0,r1),(r2,r3)
  f2 hreg2[2] = {{0.f, 0.f}, {0.f, 0.f}};
  __syncthreads();

  int p = 0;
  for (int t4 = 0; t4 < L; t4 += 4) {
    // 4 steps' worth of x per row in one b128 each
    float4 xq[4];
#pragma unroll
    for (int r = 0; r < 4; ++r)
      xq[r] = *(const float4*)&xs[(quad * 4 + r) * XSS + t4];
#pragma unroll
    for (int u = 0; u < 4; ++u) {
      // A-fragment of h(t-1): m=c16, k=kk*32+quad*8+j (single rtne-bf16)
      short8 ahi[2];
#pragma unroll
      for (int kk = 0; kk < 2; ++kk)
        ahi[kk] = *(const short8*)&hb[p][c16 * HBS + kk * 32 + quad * 8];
      f2 xv01 = {xq[0][u], xq[1][u]};
      f2 xv23 = {xq[2][u], xq[3][u]};
      floatx4 acc[4];
#pragma unroll
      for (int g = 0; g < 4; ++g) {
        f2 A2 = {An[g], An[g]}, B2 = {Bc[g], Bc[g]};
        f2 i01 = A2 * xv01 + B2;        // v_pk_fma_f32
        f2 i23 = A2 * xv23 + B2;
        acc[g] = (floatx4){i01.x, i01.y, i23.x, i23.y};
      }
#pragma unroll
      for (int kk = 0; kk < 2; ++kk) {
#pragma unroll
        for (int g = 0; g < 4; ++g)
          acc[g] = __builtin_amdgcn_mfma_f32_16x16x32_bf16(ahi[kk], Bf[g][kk], acc[g], 0, 0, 0);
      }
      // merged elementwise on cell PAIRS: packed arith, scalar trans
#pragma unroll
      for (int h = 0; h < 2; ++h) {
        f2 Gi = {acc[0][2*h], acc[0][2*h+1]};
        f2 Gf = {acc[1][2*h], acc[1][2*h+1]};
        f2 Gg = {acc[2][2*h], acc[2][2*h+1]};
        f2 Go = {acc[3][2*h], acc[3][2*h+1]};
        f2 Ei = ex2_2(Gi), Ef = ex2_2(Gf), Eg = ex2_2(Gg), Eo = ex2_2(Go);
        f2 pf = Ef + one2, pi = Ei + one2, pg = Eg + one2, mg = one2 - Eg;
        f2 pig = pi * pg;
        f2 num = creg2[h] * pig + mg * pf;
        f2 c2  = num * rcp_2(pf * pig);
        creg2[h] = c2;
        f2 Ec = ex2_2(c2 * m2l2);
        f2 po = Eo + one2, pc = Ec + one2, mc = one2 - Ec;
        f2 h2 = mc * rcp_2(po * pc);
        hreg2[h] = h2;
        int row0 = quad * 4 + 2 * h;
        hb[p ^ 1][row0 * HBS + dcol]       = (short)f2bf_rtne(h2.x);
        hb[p ^ 1][(row0 + 1) * HBS + dcol] = (short)f2bf_rtne(h2.y);
      }
      __syncthreads();
      p ^= 1;
    }
  }

  // unpack pair registers for the tail
  float creg[4] = {creg2[0].x, creg2[0].y, creg2[1].x, creg2[1].y};
  float hreg[4] = {hreg2[0].x, hreg2[0].y, hreg2[1].x, hreg2[1].y};

  // ---- tail: h_hat = h@W_aout.T+b ; f = h_hat@W_fh.T+b ; partial sums ----
  // x tile dead: xs[row][0..63] = h fp32, xs[row][64..127] = h_hat
#pragma unroll
  for (int r = 0; r < 4; ++r) xs[(quad * 4 + r) * XSS + dcol] = hreg[r];
  __syncthreads();

  float hhat[4];
#pragma unroll
  for (int r = 0; r < 4; ++r) {
    float a = b_aout[dcol];
    const float4* wa = (const float4*)(W_aout + (size_t)dcol * D);
    const float* hp = &xs[(quad * 4 + r) * XSS];
#pragma unroll
    for (int e4 = 0; e4 < 16; ++e4) {
      float4 wv = wa[e4];
      a = fmaf(wv.x, hp[e4*4+0], a); a = fmaf(wv.y, hp[e4*4+1], a);
      a = fmaf(wv.z, hp[e4*4+2], a); a = fmaf(wv.w, hp[e4*4+3], a);
    }
    hhat[r] = a;
  }
  __syncthreads();
#pragma unroll
  for (int r = 0; r < 4; ++r) xs[(quad * 4 + r) * XSS + 64 + dcol] = hhat[r];
  __syncthreads();

  float pfc = 0.0f, phs = 0.0f;
#pragma unroll
  for (int r = 0; r < 4; ++r) {
    float f = b_fh[dcol];
    const float4* wf = (const float4*)(W_fh + (size_t)dcol * D);
    const float* hp = &xs[(quad * 4 + r) * XSS + 64];
#pragma unroll
    for (int e4 = 0; e4 < 16; ++e4) {
      float4 wv = wf[e4];
      f = fmaf(wv.x, hp[e4*4+0], f); f = fmaf(wv.y, hp[e4*4+1], f);
      f = fmaf(wv.z, hp[e4*4+2], f); f = fmaf(wv.w, hp[e4*4+3], f);
    }
    pfc = fmaf(sig_plain(f), creg[r], pfc);
    phs += hhat[r];
  }
  pfc += __shfl_xor(pfc, 16); pfc += __shfl_xor(pfc, 32);
  phs += __shfl_xor(phs, 16); phs += __shfl_xor(phs, 32);
  if (quad == 0) {
    atomicAdd(acc_out + dcol, pfc);
    atomicAdd(acc_out + D + dcol, phs);
  }

  // ---- last-block finish ----
  __threadfence();
  if (tid == 0) {
    unsigned int prev = __hip_atomic_fetch_add((unsigned int*)(acc_out + 2 * D), 1u,
                                               __ATOMIC_ACQ_REL, __HIP_MEMORY_SCOPE_AGENT);
    is_last = (prev == NBLK - 1) ? 1 : 0;
  }
  __syncthreads();
  if (!is_last) return;
  __threadfence();
  if (tid < 2 * D)
    sacc[tid] = __hip_atomic_load(acc_out + tid, __ATOMIC_RELAXED, __HIP_MEMORY_SCOPE_AGENT);
  __syncthreads();
  if (tid < D) {
    const int d = tid;
    float vi = b_iouh[d], vo = b_iouh[D + d], vu = b_iouh[2 * D + d];
    for (int e = 0; e < D; ++e) {
      float hs = sacc[D + e];
      vi = fmaf(W_iouh[(size_t)d * D + e],           hs, vi);
      vo = fmaf(W_iouh[(size_t)(D + d) * D + e],     hs, vo);
      vu = fmaf(W_iouh[(size_t)(2 * D + d) * D + e], hs, vu);
    }
    float c_obj = sig_plain(vi) * tanh2(-2.0f * LOG2E * vu) + sacc[d];
    float h_obj = sig_plain(vo) * tanh2(-2.0f * LOG2E * c_obj);
    hobj[d] = h_obj;
    out[D + d] = c_obj;
  }
  __syncthreads();
  if (tid < D) {
    const int d = tid;
    float hh = b_oout[d];
    for (int e = 0; e < D; ++e) hh = fmaf(W_oout[(size_t)d * D + e], hobj[e], hh);
    out[d] = hh;
  }
}

extern "C" void kernel_launch(void* const* d_in, const int* in_sizes, int n_in,
                              void* d_out, int out_size, void* d_ws, size_t ws_size,
                              hipStream_t stream) {
  const float* x      = (const float*)d_in[0];
  const float* W_num  = (const float*)d_in[1];
  const float* b_num  = (const float*)d_in[2];
  const float* W_ih   = (const float*)d_in[3];
  const float* W_hh   = (const float*)d_in[4];
  const float* b_ih   = (const float*)d_in[5];
  const float* b_hh   = (const float*)d_in[6];
  const float* W_aout = (const float*)d_in[7];
  const float* b_aout = (const float*)d_in[8];
  const float* W_fh   = (const float*)d_in[9];
  const float* b_fh   = (const float*)d_in[10];
  const float* W_iouh = (const float*)d_in[11];
  const float* b_iouh = (const float*)d_in[12];
  const float* W_oout = (const float*)d_in[13];
  const float* b_oout = (const float*)d_in[14];
  float* acc = (float*)d_ws;
  float* out = (float*)d_out;

  hipMemsetAsync(d_ws, 0, (2 * D + 1) * sizeof(float), stream);
  lstm_main<<<NBLK, NT, 0, stream>>>(x, W_num, b_num, W_ih, W_hh, b_ih, b_hh,
                                     W_aout, b_aout, W_fh, b_fh,
                                     W_iouh, b_iouh, W_oout, b_oout, acc, out);
}